// Round 8
// baseline (520.279 us; speedup 1.0000x reference)
//
#include <hip/hip_runtime.h>
#include <hip/hip_bf16.h>
#include <stdint.h>

typedef unsigned short u16;
typedef __bf16 bf16_8 __attribute__((ext_vector_type(8)));
typedef float f32x4 __attribute__((ext_vector_type(4)));

#define SEQ 2048
#define DIM 4096
#define NH 32
#define NKV 8
#define HD 128
// 1/sqrt(128) * log2(e)  -- exp2-based softmax, scale folded into Q epilogue
#define QSCALE_LOG2E 0.12753785222167917f

__device__ inline u16 f2bf(float f) {
    unsigned int u = __float_as_uint(f);
    unsigned int r = (u + 0x7fffu + ((u >> 16) & 1u)) >> 16;
    return (u16)r;
}

__device__ inline void async16(const void* g, void* l) {
    __builtin_amdgcn_global_load_lds(
        (const __attribute__((address_space(1))) void*)g,
        (__attribute__((address_space(3))) void*)l, 16, 0, 0);
}

// ---------------- fused fp32 -> bf16 cast of all 5 tensors ----------------
__global__ __launch_bounds__(256) void cast_all(const float* __restrict__ x,
                                                const float* __restrict__ wq,
                                                const float* __restrict__ wk,
                                                const float* __restrict__ wv,
                                                const float* __restrict__ wo,
                                                u16* __restrict__ dst) {
    size_t i4 = (size_t)blockIdx.x * 256 + threadIdx.x;  // float4 group index
    size_t e = i4 * 4;                                   // element index
    const float* src;
    size_t off;  // segment start (elements)
    if (e < 8388608ull)       { src = x;  off = 0; }
    else if (e < 25165824ull) { src = wq; off = 8388608ull; }
    else if (e < 29360128ull) { src = wk; off = 25165824ull; }
    else if (e < 33554432ull) { src = wv; off = 29360128ull; }
    else                      { src = wo; off = 33554432ull; }
    float4 v = ((const float4*)src)[i4 - off / 4];
    ushort4 o;
    o.x = f2bf(v.x); o.y = f2bf(v.y); o.z = f2bf(v.z); o.w = f2bf(v.w);
    ((ushort4*)dst)[i4] = o;
}

// ============ GEMM core: C[M,N] = A[M,K] * B[N,K]^T (bf16, fp32 acc) =======
// m97-class structure (round-0 verified): 128x128 tile, BK=32, 256 threads
// (4 waves 2x2, wave tile 64x64), SINGLE-buffer LDS (16 KB), async16
// (global_load_lds width 16) staging, two __syncthreads per K-tile.  The
// compiler's vmcnt(0) drain at the barrier is hidden by 3-4 blocks/CU TLP
// (m114 wave-level overlap) -- T_tile ~2020 cyc at 3 blocks/CU (m97: 912 TF).
// Round 1-5 lesson: this structure was never compute-slow; it was FETCH-bound
// (345 MB) under the 1D bn-major XCD swizzle.  Fix kept from rounds 6/7:
// 2D XCD partition (bijective, per-XCD L2 fill = A/2 + B/4 ~= 20 MB; measured
// FETCH 405 -> 136 MB).  LDS chunk-XOR layout: 0 bank conflicts (measured).
// MODE 0: fp32 row-major out (out-proj)
// MODE 1: QKV-routed epilogue with fused RoPE (Q pre-scaled by QSCALE_LOG2E)
template <int MODE>
__global__ __launch_bounds__(256) void gemm_bt(const u16* __restrict__ A,
                                               const u16* __restrict__ B,
                                               void* __restrict__ C0,
                                               void* __restrict__ C1,
                                               void* __restrict__ C2,
                                               const float* __restrict__ fc,
                                               const float* __restrict__ fs,
                                               int M, int N, int K) {
    __shared__ u16 As[128 * 32];
    __shared__ u16 Bs[128 * 32];
    const int tid = threadIdx.x;
    const int lane = tid & 63;
    const int wid = tid >> 6;
    const int quad = lane >> 4;
    const int l16 = lane & 15;
    const int wm = (wid >> 1) * 64;
    const int wn = (wid & 1) * 64;

    // ---- 2D XCD partition (bijective; gy%2==0, gx%4==0 for both grids).
    // HW round-robins consecutive ids over 8 XCDs (xcd = id&7); give each XCD
    // a contiguous (gy/2 x gx/4) sub-grid -> per-XCD L2 fill = A/2 + B/4.
    const int gx = gridDim.x, gy = gridDim.y;
    int id = blockIdx.y * gx + blockIdx.x;
    const int xcd = id & 7;
    const int j = id >> 3;
    const int hy = gy >> 1;
    const int jm = j % hy;
    const int jn = j / hy;
    const int bm = ((xcd >> 2) * hy + jm) * 128;
    const int bn = ((xcd & 3) * (gx >> 2) + jn) * 128;

    f32x4 acc[4][4] = {};

    for (int k0 = 0; k0 < K; k0 += 32) {
#pragma unroll
        for (int r = 0; r < 2; ++r) {
            int S = r * 256 + tid;          // chunk slot 0..511
            int row = S >> 2;
            int slot = S & 3;
            int chunk = slot ^ ((row >> 1) & 3);
            const char* ga = (const char*)A + ((size_t)(bm + row) * K + k0 + chunk * 8) * 2;
            async16(ga, (char*)As + S * 16);
            const char* gb = (const char*)B + ((size_t)(bn + row) * K + k0 + chunk * 8) * 2;
            async16(gb, (char*)Bs + S * 16);
        }
        __syncthreads();
        const int cs = quad ^ ((l16 >> 1) & 3);  // swizzled chunk position
        bf16_8 a[4], b[4];
#pragma unroll
        for (int i = 0; i < 4; ++i)
            a[i] = *(const bf16_8*)&As[(wm + i * 16 + l16) * 32 + cs * 8];
#pragma unroll
        for (int j2 = 0; j2 < 4; ++j2)
            b[j2] = *(const bf16_8*)&Bs[(wn + j2 * 16 + l16) * 32 + cs * 8];
#pragma unroll
        for (int i = 0; i < 4; ++i)
#pragma unroll
            for (int j2 = 0; j2 < 4; ++j2)
                acc[i][j2] = __builtin_amdgcn_mfma_f32_16x16x32_bf16(a[i], b[j2], acc[i][j2], 0, 0, 0);
        __syncthreads();
    }

    if (MODE == 0) {
        float* Cf = (float*)C0;
#pragma unroll
        for (int i = 0; i < 4; ++i)
#pragma unroll
            for (int j2 = 0; j2 < 4; ++j2)
#pragma unroll
                for (int r = 0; r < 4; ++r)
                    Cf[(size_t)(bm + wm + i * 16 + quad * 4 + r) * N + (bn + wn + j2 * 16 + l16)] =
                        acc[i][j2][r];
    } else {
        // QKV routing; bn is a multiple of 128 so the whole block takes one branch
        u16* Qb = (u16*)C0;
        u16* Kb = (u16*)C1;
        u16* Vt = (u16*)C2;
        if (bn < 5120) {
            const bool isQ = bn < 4096;
            const float osc = isQ ? QSCALE_LOG2E : 1.0f;
#pragma unroll
            for (int i = 0; i < 4; ++i)
#pragma unroll
                for (int j2 = 0; j2 < 4; ++j2) {
                    int n = bn + wn + j2 * 16 + l16;
                    int pp = (n & 127) >> 1;
                    bool odd = (l16 & 1);
#pragma unroll
                    for (int r = 0; r < 4; ++r) {
                        int m = bm + wm + i * 16 + quad * 4 + r;
                        float v = acc[i][j2][r];
                        float u = __shfl_xor(v, 1);
                        float c = fc[m * 64 + pp];
                        float s = fs[m * 64 + pp];
                        float o = (odd ? (u * s + v * c) : (v * c - u * s)) * osc;
                        if (isQ)
                            Qb[(size_t)m * 4096 + n] = f2bf(o);
                        else
                            Kb[(size_t)m * 1024 + (n - 4096)] = f2bf(o);
                    }
                }
        } else {
            // V range: store transposed (d-major), no rope
#pragma unroll
            for (int i = 0; i < 4; ++i)
#pragma unroll
                for (int j2 = 0; j2 < 4; ++j2) {
                    int n = bn + wn + j2 * 16 + l16;
                    ushort4 o;
                    o.x = f2bf(acc[i][j2][0]);
                    o.y = f2bf(acc[i][j2][1]);
                    o.z = f2bf(acc[i][j2][2]);
                    o.w = f2bf(acc[i][j2][3]);
                    *(ushort4*)&Vt[(size_t)(n - 5120) * SEQ + (bm + wm + i * 16 + quad * 4)] = o;
                }
        }
    }
}

// ---------------- Flash attention, S^T formulation (unchanged) ----------------
__global__ __launch_bounds__(256, 4) void attn_k(const u16* __restrict__ Q,
                                                 const u16* __restrict__ Kb,
                                                 const u16* __restrict__ Vt,
                                                 u16* __restrict__ Y) {
    __shared__ u16 Ks[64 * 128];   // swizzled: 16B chunks, slot = c ^ (row&15)
    __shared__ u16 Vs[128 * 64];   // swizzled: 16B chunks, slot = c ^ (row&7)
    __shared__ u16 Ps[4 * 16 * 64];// per-wave 2 KB; 8B chunks, c' = c ^ ((l16&7)<<1)
    const int tid = threadIdx.x;
    const int lane = tid & 63;
    const int w = tid >> 6;
    const int quad = lane >> 4;
    const int l16 = lane & 15;
    const int id = blockIdx.x;
    const int qt = 31 - (id >> 5);   // LPT: longest blocks first
    const int h = id & 31;
    const int kvh = h >> 2;
    const size_t qrow0 = (size_t)qt * 64;

    bf16_8 qf[4];
#pragma unroll
    for (int ks = 0; ks < 4; ++ks)
        qf[ks] = *(const bf16_8*)&Q[(qrow0 + w * 16 + l16) * DIM + h * HD + ks * 32 + quad * 8];

    f32x4 po[8] = {};    // 16 x 128 unnormalized output accumulator
    float lsum = 0.f;    // per-lane partial row sum for q-row l16

    char* psbase = (char*)Ps + w * 2048 + l16 * 128;  // this lane's P row
    const int sw = (l16 & 7) << 1;                    // 8B-chunk swizzle

    for (int kt = 0; kt <= qt; ++kt) {
#pragma unroll
        for (int r = 0; r < 4; ++r) {
            int S = r * 256 + tid;  // 0..1023
            {
                int row = S >> 4, slot = S & 15;
                int chunk = slot ^ (row & 15);
                const char* g = (const char*)Kb +
                    (((size_t)kt * 64 + row) * 1024 + kvh * HD + chunk * 8) * 2;
                async16(g, (char*)Ks + S * 16);
            }
            {
                int row = S >> 3, slot = S & 7;
                int chunk = slot ^ (row & 7);
                const char* g = (const char*)Vt +
                    (((size_t)(kvh * HD + row)) * SEQ + kt * 64 + chunk * 8) * 2;
                async16(g, (char*)Vs + S * 16);
            }
        }
        __syncthreads();

        f32x4 sc[4] = {};
#pragma unroll
        for (int ks = 0; ks < 4; ++ks)
#pragma unroll
            for (int jb = 0; jb < 4; ++jb) {
                bf16_8 kb = *(const bf16_8*)&Ks[(jb * 16 + l16) * 128 + ((ks * 4 + quad) ^ l16) * 8];
                sc[jb] = __builtin_amdgcn_mfma_f32_16x16x32_bf16(kb, qf[ks], sc[jb], 0, 0, 0);
            }

        float pv[4][4];
#pragma unroll
        for (int jb = 0; jb < 4; ++jb)
#pragma unroll
            for (int r = 0; r < 4; ++r)
                pv[jb][r] = exp2f(sc[jb][r]);

        if (kt == qt) {  // wave-uniform: mask k > q on the diagonal tile
            int qloc = w * 16 + l16;
#pragma unroll
            for (int jb = 0; jb < 4; ++jb)
#pragma unroll
                for (int r = 0; r < 4; ++r)
                    if (jb * 16 + quad * 4 + r > qloc) pv[jb][r] = 0.f;
        }

#pragma unroll
        for (int jb = 0; jb < 4; ++jb) {
            lsum += (pv[jb][0] + pv[jb][1]) + (pv[jb][2] + pv[jb][3]);
            ushort4 pk;
            pk.x = f2bf(pv[jb][0]);
            pk.y = f2bf(pv[jb][1]);
            pk.z = f2bf(pv[jb][2]);
            pk.w = f2bf(pv[jb][3]);
            int c = jb * 4 + quad;
            *(ushort4*)(psbase + ((c ^ sw) << 3)) = pk;
        }

#pragma unroll
        for (int ks = 0; ks < 2; ++ks) {
            int c = ks * 8 + quad * 2;
            bf16_8 pf = *(const bf16_8*)(psbase + ((c ^ sw) << 3));
#pragma unroll
            for (int n = 0; n < 8; ++n) {
                bf16_8 vf = *(const bf16_8*)&Vs[(n * 16 + l16) * 64 + (((ks * 4 + quad) ^ (l16 & 7))) * 8];
                po[n] = __builtin_amdgcn_mfma_f32_16x16x32_bf16(pf, vf, po[n], 0, 0, 0);
            }
        }
        __syncthreads();
    }

    lsum += __shfl_xor(lsum, 16);
    lsum += __shfl_xor(lsum, 32);
    float inv = 1.f / lsum;
#pragma unroll
    for (int r = 0; r < 4; ++r) {
        float invr = __shfl(inv, quad * 4 + r);
        size_t row = qrow0 + w * 16 + quad * 4 + r;
#pragma unroll
        for (int n = 0; n < 8; ++n)
            Y[row * DIM + h * HD + n * 16 + l16] = f2bf(po[n][r] * invr);
    }
}

extern "C" void kernel_launch(void* const* d_in, const int* in_sizes, int n_in,
                              void* d_out, int out_size, void* d_ws, size_t ws_size,
                              hipStream_t stream) {
    const float* x  = (const float*)d_in[0];
    const float* wq = (const float*)d_in[1];
    const float* wk = (const float*)d_in[2];
    const float* wv = (const float*)d_in[3];
    const float* wo = (const float*)d_in[4];
    const float* fc = (const float*)d_in[5];
    const float* fs = (const float*)d_in[6];

    char* ws = (char*)d_ws;
    const size_t MB = 1u << 20;
    u16* xb    = (u16*)(ws);             // 2048x4096 bf16       (16 MB)
    u16* wqkvb = (u16*)(ws + 16 * MB);   // 6144x4096 (wq|wk|wv) (48 MB)
    u16* wob   = (u16*)(ws + 64 * MB);   // 4096x4096            (32 MB)
    u16* Qb    = (u16*)(ws + 96 * MB);   // 2048x4096            (16 MB)
    u16* Kb    = (u16*)(ws + 112 * MB);  // 2048x1024            (4 MB)
    u16* Vtb   = (u16*)(ws + 116 * MB);  // 1024x2048 (V^T)      (4 MB)
    u16* Yb    = (u16*)(ws + 120 * MB);  // 2048x4096            (16 MB)

    // single fused cast: [x | wq | wk | wv | wo] -> bf16 at ws[0..96MB)
    cast_all<<<49152, 256, 0, stream>>>(x, wq, wk, wv, wo, (u16*)ws);

    // fused QKV projection + RoPE (+ Q pre-scale incl. log2e) epilogue
    gemm_bt<1><<<dim3(48, 16), 256, 0, stream>>>(xb, wqkvb, Qb, Kb, Vtb, fc, fs,
                                                 2048, 6144, 4096);

    // attention (LPT-ordered 1D grid)
    attn_k<<<dim3(1024), 256, 0, stream>>>(Qb, Kb, Vtb, Yb);

    // output projection -> fp32 d_out
    gemm_bt<0><<<dim3(32, 16), 256, 0, stream>>>(Yb, wob, (float*)d_out, nullptr, nullptr,
                                                 nullptr, nullptr, 2048, 4096, 4096);
}

// Round 9
// 469.973 us; speedup vs baseline: 1.1070x; 1.1070x over previous
//
#include <hip/hip_runtime.h>
#include <hip/hip_bf16.h>
#include <stdint.h>

typedef unsigned short u16;
typedef __bf16 bf16_8 __attribute__((ext_vector_type(8)));
typedef float f32x4 __attribute__((ext_vector_type(4)));

#define SEQ 2048
#define DIM 4096
#define NH 32
#define NKV 8
#define HD 128
// 1/sqrt(128) * log2(e)  -- exp2-based softmax, scale folded into Q epilogue
#define QSCALE_LOG2E 0.12753785222167917f

__device__ inline u16 f2bf(float f) {
    unsigned int u = __float_as_uint(f);
    unsigned int r = (u + 0x7fffu + ((u >> 16) & 1u)) >> 16;
    return (u16)r;
}

__device__ inline void async16(const void* g, void* l) {
    __builtin_amdgcn_global_load_lds(
        (const __attribute__((address_space(1))) void*)g,
        (__attribute__((address_space(3))) void*)l, 16, 0, 0);
}

// ---------------- fused fp32 -> bf16 cast of all 5 tensors ----------------
__global__ __launch_bounds__(256) void cast_all(const float* __restrict__ x,
                                                const float* __restrict__ wq,
                                                const float* __restrict__ wk,
                                                const float* __restrict__ wv,
                                                const float* __restrict__ wo,
                                                u16* __restrict__ dst) {
    size_t i4 = (size_t)blockIdx.x * 256 + threadIdx.x;  // float4 group index
    size_t e = i4 * 4;                                   // element index
    const float* src;
    size_t off;  // segment start (elements)
    if (e < 8388608ull)       { src = x;  off = 0; }
    else if (e < 25165824ull) { src = wq; off = 8388608ull; }
    else if (e < 29360128ull) { src = wk; off = 25165824ull; }
    else if (e < 33554432ull) { src = wv; off = 29360128ull; }
    else                      { src = wo; off = 33554432ull; }
    float4 v = ((const float4*)src)[i4 - off / 4];
    ushort4 o;
    o.x = f2bf(v.x); o.y = f2bf(v.y); o.z = f2bf(v.z); o.w = f2bf(v.w);
    ((ushort4*)dst)[i4] = o;
}

// ============ GEMM core: C[M,N] = A[M,K] * B[N,K]^T (bf16, fp32 acc) =======
// Round-8 diagnosis: wall = NT x T_serial per block (out-proj @2blk/CU ==
// QKV @3blk/CU == 128 tiles x ~3000cyc; MfmaUtil 28%, VALUBusy 42% -- chain-
// bound, not resource-bound).  Fix: BK 32 -> 64 halves NT; T_serial grows
// sub-linearly (extra ds_read+MFMA phase rides inside the same drain; the
// vmcnt(0)+barrier drain is paid once per 64 K-elems).  Single-buffer LDS
// 32 KB (As/Bs 16 KB each), two __syncthreads per K-tile, async16 staging.
// 8-chunk row swizzle (slot = ch ^ (row&7)) == attn Ks layout, measured
// conflict-free; read slot (ks*4+quad)^(l16&7) -> global chunk ks*4+quad.
// 2D XCD partition kept (FETCH 405 -> 84 MB measured).
// MODE 0: fp32 row-major out (out-proj)
// MODE 1: QKV-routed epilogue with fused RoPE (Q pre-scaled by QSCALE_LOG2E)
template <int MODE>
__global__ __launch_bounds__(256) void gemm_bt(const u16* __restrict__ A,
                                               const u16* __restrict__ B,
                                               void* __restrict__ C0,
                                               void* __restrict__ C1,
                                               void* __restrict__ C2,
                                               const float* __restrict__ fc,
                                               const float* __restrict__ fs,
                                               int M, int N, int K) {
    __shared__ u16 As[128 * 64];
    __shared__ u16 Bs[128 * 64];
    const int tid = threadIdx.x;
    const int lane = tid & 63;
    const int wid = tid >> 6;
    const int quad = lane >> 4;
    const int l16 = lane & 15;
    const int wm = (wid >> 1) * 64;
    const int wn = (wid & 1) * 64;

    // ---- 2D XCD partition (bijective; gy%2==0, gx%4==0 for both grids).
    // HW round-robins consecutive ids over 8 XCDs (xcd = id&7); give each XCD
    // a contiguous (gy/2 x gx/4) sub-grid -> per-XCD L2 fill = A/2 + B/4.
    const int gx = gridDim.x, gy = gridDim.y;
    int id = blockIdx.y * gx + blockIdx.x;
    const int xcd = id & 7;
    const int j = id >> 3;
    const int hy = gy >> 1;
    const int jm = j % hy;
    const int jn = j / hy;
    const int bm = ((xcd >> 2) * hy + jm) * 128;
    const int bn = ((xcd & 3) * (gx >> 2) + jn) * 128;

    f32x4 acc[4][4] = {};

    for (int k0 = 0; k0 < K; k0 += 64) {
        // stage 128x64 A and B tiles: 4 async16 each per thread
#pragma unroll
        for (int r = 0; r < 4; ++r) {
            int S = r * 256 + tid;          // chunk slot 0..1023
            int row = S >> 3;
            int slot = S & 7;
            int chunk = slot ^ (row & 7);
            const char* ga = (const char*)A + ((size_t)(bm + row) * K + k0 + chunk * 8) * 2;
            async16(ga, (char*)As + S * 16);
            const char* gb = (const char*)B + ((size_t)(bn + row) * K + k0 + chunk * 8) * 2;
            async16(gb, (char*)Bs + S * 16);
        }
        __syncthreads();
#pragma unroll
        for (int ks = 0; ks < 2; ++ks) {
            const int cs = (ks * 4 + quad) ^ (l16 & 7);  // swizzled chunk slot
            bf16_8 a[4], b[4];
#pragma unroll
            for (int i = 0; i < 4; ++i)
                a[i] = *(const bf16_8*)&As[(wm + i * 16 + l16) * 64 + cs * 8];
#pragma unroll
            for (int j2 = 0; j2 < 4; ++j2)
                b[j2] = *(const bf16_8*)&Bs[(wn + j2 * 16 + l16) * 64 + cs * 8];
#pragma unroll
            for (int i = 0; i < 4; ++i)
#pragma unroll
                for (int j2 = 0; j2 < 4; ++j2)
                    acc[i][j2] = __builtin_amdgcn_mfma_f32_16x16x32_bf16(a[i], b[j2], acc[i][j2], 0, 0, 0);
        }
        __syncthreads();
    }

    if (MODE == 0) {
        float* Cf = (float*)C0;
#pragma unroll
        for (int i = 0; i < 4; ++i)
#pragma unroll
            for (int j2 = 0; j2 < 4; ++j2)
#pragma unroll
                for (int r = 0; r < 4; ++r)
                    Cf[(size_t)(bm + wm + i * 16 + quad * 4 + r) * N + (bn + wn + j2 * 16 + l16)] =
                        acc[i][j2][r];
    } else {
        // QKV routing; bn is a multiple of 128 so the whole block takes one branch
        u16* Qb = (u16*)C0;
        u16* Kb = (u16*)C1;
        u16* Vt = (u16*)C2;
        if (bn < 5120) {
            const bool isQ = bn < 4096;
            const float osc = isQ ? QSCALE_LOG2E : 1.0f;
#pragma unroll
            for (int i = 0; i < 4; ++i)
#pragma unroll
                for (int j2 = 0; j2 < 4; ++j2) {
                    int n = bn + wn + j2 * 16 + l16;
                    int pp = (n & 127) >> 1;
                    bool odd = (l16 & 1);
#pragma unroll
                    for (int r = 0; r < 4; ++r) {
                        int m = bm + wm + i * 16 + quad * 4 + r;
                        float v = acc[i][j2][r];
                        float u = __shfl_xor(v, 1);
                        float c = fc[m * 64 + pp];
                        float s = fs[m * 64 + pp];
                        float o = (odd ? (u * s + v * c) : (v * c - u * s)) * osc;
                        if (isQ)
                            Qb[(size_t)m * 4096 + n] = f2bf(o);
                        else
                            Kb[(size_t)m * 1024 + (n - 4096)] = f2bf(o);
                    }
                }
        } else {
            // V range: store transposed (d-major), no rope
#pragma unroll
            for (int i = 0; i < 4; ++i)
#pragma unroll
                for (int j2 = 0; j2 < 4; ++j2) {
                    int n = bn + wn + j2 * 16 + l16;
                    ushort4 o;
                    o.x = f2bf(acc[i][j2][0]);
                    o.y = f2bf(acc[i][j2][1]);
                    o.z = f2bf(acc[i][j2][2]);
                    o.w = f2bf(acc[i][j2][3]);
                    *(ushort4*)&Vt[(size_t)(n - 5120) * SEQ + (bm + wm + i * 16 + quad * 4)] = o;
                }
        }
    }
}

// ---------------- Flash attention, S^T formulation (unchanged) ----------------
__global__ __launch_bounds__(256, 4) void attn_k(const u16* __restrict__ Q,
                                                 const u16* __restrict__ Kb,
                                                 const u16* __restrict__ Vt,
                                                 u16* __restrict__ Y) {
    __shared__ u16 Ks[64 * 128];   // swizzled: 16B chunks, slot = c ^ (row&15)
    __shared__ u16 Vs[128 * 64];   // swizzled: 16B chunks, slot = c ^ (row&7)
    __shared__ u16 Ps[4 * 16 * 64];// per-wave 2 KB; 8B chunks, c' = c ^ ((l16&7)<<1)
    const int tid = threadIdx.x;
    const int lane = tid & 63;
    const int w = tid >> 6;
    const int quad = lane >> 4;
    const int l16 = lane & 15;
    const int id = blockIdx.x;
    const int qt = 31 - (id >> 5);   // LPT: longest blocks first
    const int h = id & 31;
    const int kvh = h >> 2;
    const size_t qrow0 = (size_t)qt * 64;

    bf16_8 qf[4];
#pragma unroll
    for (int ks = 0; ks < 4; ++ks)
        qf[ks] = *(const bf16_8*)&Q[(qrow0 + w * 16 + l16) * DIM + h * HD + ks * 32 + quad * 8];

    f32x4 po[8] = {};    // 16 x 128 unnormalized output accumulator
    float lsum = 0.f;    // per-lane partial row sum for q-row l16

    char* psbase = (char*)Ps + w * 2048 + l16 * 128;  // this lane's P row
    const int sw = (l16 & 7) << 1;                    // 8B-chunk swizzle

    for (int kt = 0; kt <= qt; ++kt) {
#pragma unroll
        for (int r = 0; r < 4; ++r) {
            int S = r * 256 + tid;  // 0..1023
            {
                int row = S >> 4, slot = S & 15;
                int chunk = slot ^ (row & 15);
                const char* g = (const char*)Kb +
                    (((size_t)kt * 64 + row) * 1024 + kvh * HD + chunk * 8) * 2;
                async16(g, (char*)Ks + S * 16);
            }
            {
                int row = S >> 3, slot = S & 7;
                int chunk = slot ^ (row & 7);
                const char* g = (const char*)Vt +
                    (((size_t)(kvh * HD + row)) * SEQ + kt * 64 + chunk * 8) * 2;
                async16(g, (char*)Vs + S * 16);
            }
        }
        __syncthreads();

        f32x4 sc[4] = {};
#pragma unroll
        for (int ks = 0; ks < 4; ++ks)
#pragma unroll
            for (int jb = 0; jb < 4; ++jb) {
                bf16_8 kb = *(const bf16_8*)&Ks[(jb * 16 + l16) * 128 + ((ks * 4 + quad) ^ l16) * 8];
                sc[jb] = __builtin_amdgcn_mfma_f32_16x16x32_bf16(kb, qf[ks], sc[jb], 0, 0, 0);
            }

        float pv[4][4];
#pragma unroll
        for (int jb = 0; jb < 4; ++jb)
#pragma unroll
            for (int r = 0; r < 4; ++r)
                pv[jb][r] = exp2f(sc[jb][r]);

        if (kt == qt) {  // wave-uniform: mask k > q on the diagonal tile
            int qloc = w * 16 + l16;
#pragma unroll
            for (int jb = 0; jb < 4; ++jb)
#pragma unroll
                for (int r = 0; r < 4; ++r)
                    if (jb * 16 + quad * 4 + r > qloc) pv[jb][r] = 0.f;
        }

#pragma unroll
        for (int jb = 0; jb < 4; ++jb) {
            lsum += (pv[jb][0] + pv[jb][1]) + (pv[jb][2] + pv[jb][3]);
            ushort4 pk;
            pk.x = f2bf(pv[jb][0]);
            pk.y = f2bf(pv[jb][1]);
            pk.z = f2bf(pv[jb][2]);
            pk.w = f2bf(pv[jb][3]);
            int c = jb * 4 + quad;
            *(ushort4*)(psbase + ((c ^ sw) << 3)) = pk;
        }

#pragma unroll
        for (int ks = 0; ks < 2; ++ks) {
            int c = ks * 8 + quad * 2;
            bf16_8 pf = *(const bf16_8*)(psbase + ((c ^ sw) << 3));
#pragma unroll
            for (int n = 0; n < 8; ++n) {
                bf16_8 vf = *(const bf16_8*)&Vs[(n * 16 + l16) * 64 + (((ks * 4 + quad) ^ (l16 & 7))) * 8];
                po[n] = __builtin_amdgcn_mfma_f32_16x16x32_bf16(pf, vf, po[n], 0, 0, 0);
            }
        }
        __syncthreads();
    }

    lsum += __shfl_xor(lsum, 16);
    lsum += __shfl_xor(lsum, 32);
    float inv = 1.f / lsum;
#pragma unroll
    for (int r = 0; r < 4; ++r) {
        float invr = __shfl(inv, quad * 4 + r);
        size_t row = qrow0 + w * 16 + quad * 4 + r;
#pragma unroll
        for (int n = 0; n < 8; ++n)
            Y[row * DIM + h * HD + n * 16 + l16] = f2bf(po[n][r] * invr);
    }
}

extern "C" void kernel_launch(void* const* d_in, const int* in_sizes, int n_in,
                              void* d_out, int out_size, void* d_ws, size_t ws_size,
                              hipStream_t stream) {
    const float* x  = (const float*)d_in[0];
    const float* wq = (const float*)d_in[1];
    const float* wk = (const float*)d_in[2];
    const float* wv = (const float*)d_in[3];
    const float* wo = (const float*)d_in[4];
    const float* fc = (const float*)d_in[5];
    const float* fs = (const float*)d_in[6];

    char* ws = (char*)d_ws;
    const size_t MB = 1u << 20;
    u16* xb    = (u16*)(ws);             // 2048x4096 bf16       (16 MB)
    u16* wqkvb = (u16*)(ws + 16 * MB);   // 6144x4096 (wq|wk|wv) (48 MB)
    u16* wob   = (u16*)(ws + 64 * MB);   // 4096x4096            (32 MB)
    u16* Qb    = (u16*)(ws + 96 * MB);   // 2048x4096            (16 MB)
    u16* Kb    = (u16*)(ws + 112 * MB);  // 2048x1024            (4 MB)
    u16* Vtb   = (u16*)(ws + 116 * MB);  // 1024x2048 (V^T)      (4 MB)
    u16* Yb    = (u16*)(ws + 120 * MB);  // 2048x4096            (16 MB)

    // single fused cast: [x | wq | wk | wv | wo] -> bf16 at ws[0..96MB)
    cast_all<<<49152, 256, 0, stream>>>(x, wq, wk, wv, wo, (u16*)ws);

    // fused QKV projection + RoPE (+ Q pre-scale incl. log2e) epilogue
    gemm_bt<1><<<dim3(48, 16), 256, 0, stream>>>(xb, wqkvb, Qb, Kb, Vtb, fc, fs,
                                                 2048, 6144, 4096);

    // attention (LPT-ordered 1D grid)
    attn_k<<<dim3(1024), 256, 0, stream>>>(Qb, Kb, Vtb, Yb);

    // output projection -> fp32 d_out
    gemm_bt<0><<<dim3(32, 16), 256, 0, stream>>>(Yb, wob, (float*)d_out, nullptr, nullptr,
                                                 nullptr, nullptr, 2048, 4096, 4096);
}